// Round 9
// baseline (118.714 us; speedup 1.0000x reference)
//
#include <hip/hip_runtime.h>
#include <hip/hip_bf16.h>

typedef __attribute__((ext_vector_type(4))) float  f32x4;
typedef __attribute__((ext_vector_type(8))) _Float16 f16x8;

// ---- weight pre-transform: w1 -> Bt1[64 n][32 k] f16; w2 -> Bt2[9 tap][128 c2][64 c1] f16
__global__ void transform_kernel(const float* __restrict__ w1, const float* __restrict__ w2,
                                 _Float16* __restrict__ Bt1, _Float16* __restrict__ Bt2)
{
    const int i = blockIdx.x * 256 + threadIdx.x;
    if (i < 64 * 32) {
        const int n = i >> 5, k = i & 31;
        const float v = (k < 27) ? w1[n * 27 + k] : 0.0f;
        Bt1[i] = (_Float16)v;
    }
    const int j = i - 64 * 32;
    if (j >= 0 && j < 9 * 128 * 64) {
        const int tap = j / (128 * 64);
        const int rem = j % (128 * 64);
        const int n = rem >> 6;          // c2
        const int c1 = rem & 63;
        Bt2[j] = (_Float16)w2[((size_t)n * 64 + c1) * 9 + tap];
    }
}

// ---- fused gather + conv1 + conv2. Block = (mc: 4 out-rows, img). 256 thr, 4 waves.
// h1 slab (9 rows x 64 px x 64 c1, parity-split + XOR-swizzled) lives in LDS only.
// conv2: wave tile 64x64, A from LDS slab, B register-prefetched from L2-resident Bt2.
__global__ __launch_bounds__(256, 1) void fused_kernel(
    const float* __restrict__ x, const float* __restrict__ l,
    const _Float16* __restrict__ Bt1, const float* __restrict__ b1,
    const _Float16* __restrict__ Bt2, const float* __restrict__ b2,
    float* __restrict__ out)
{
    const int bk = blockIdx.y;               // 0..191
    const int mc = blockIdx.x;               // 0..7 : out-rows 4mc..4mc+3
    const int b  = bk / 3, ksc = bk % 3;
    const int step = 1 << ksc;
    const int half = 32 << ksc;
    const int y0 = mc * 8;                   // first h1 row of the 9-row slab

    const int t = threadIdx.x, wave = t >> 6, lane = t & 63;
    const int lrow = lane & 15, kb = lane >> 4;
    const int wq = wave >> 1, wn = wave & 1; // 2x2 wave grid: M-half / N-half

    __shared__ float    patch[3 * 11 * 66]; // 8712 B unique gather window
    __shared__ _Float16 A1[192 * 40];       // 15360 B im2col (3-row chunks)
    __shared__ _Float16 slab[576 * 64];     // 73728 B h1 slab (9 rows)

    const float ly = l[b * 2 + 0], lx = l[b * 2 + 1];
    int cy = (int)floorf(0.5f * (ly + 1.0f) * 512.0f);
    int cx = (int)floorf(0.5f * (lx + 1.0f) * 512.0f);
    cy = min(max(cy, 0), 512);
    cx = min(max(cx, 0), 512);
    const int sy = cy - half, sx = cx - half;

    // ---- phase 0: gather 11x66 patch (rows y0-1 .. y0+9), 3 channels
    const float* xb = x + (size_t)b * 3 * 262144;
    for (int i = t; i < 3 * 11 * 66; i += 256) {
        const int c = i / 726, r = i % 726;
        const int ry = r / 66, xx = r % 66;
        const int yy = y0 - 1 + ry, col = xx - 1;
        const int iy = sy + yy * step, ix = sx + col * step;
        float v = 0.0f;
        if (yy >= 0 && yy < 64 && col >= 0 && col < 64 &&
            iy >= 0 && iy < 512 && ix >= 0 && ix < 512)
            v = xb[(size_t)c * 262144 + iy * 512 + ix];
        patch[i] = v;
    }

    // per-lane weight/bias registers
    f16x8 w1f[4];
    float b1v[4], b2v[4];
    #pragma unroll
    for (int nf = 0; nf < 4; ++nf) {
        w1f[nf] = *(const f16x8*)(Bt1 + ((size_t)(nf * 16 + lrow)) * 32 + kb * 8);
        b1v[nf] = b1[nf * 16 + lrow];
        b2v[nf] = b2[wn * 64 + nf * 16 + lrow];
    }
    __syncthreads();

    // ---- phase 1: conv1 -> slab, 3 chunks of 192 px (3 h1-rows each)
    #pragma unroll 1
    for (int ch = 0; ch < 3; ++ch) {
        if (t < 192) {                       // im2col from patch
            const int pyl = 3 * ch + (t >> 6), px = t & 63;
            _Float16* arow = &A1[t * 40];
            #pragma unroll
            for (int k = 0; k < 27; ++k) {
                const int c = k / 9, rr = k % 9, kh = rr / 3, kw = rr % 3;
                arow[k] = (_Float16)patch[c * 726 + (pyl + kh) * 66 + (px + kw)];
            }
            #pragma unroll
            for (int k = 27; k < 32; ++k) arow[k] = (_Float16)0.0f;
        }
        __syncthreads();

        f32x4 acc1[3][4];
        #pragma unroll
        for (int mf = 0; mf < 3; ++mf)
            #pragma unroll
            for (int nf = 0; nf < 4; ++nf)
                #pragma unroll
                for (int r = 0; r < 4; ++r) acc1[mf][nf][r] = 0.0f;

        #pragma unroll
        for (int mf = 0; mf < 3; ++mf) {
            const f16x8 afr = *(const f16x8*)&A1[((wave * 3 + mf) * 16 + lrow) * 40 + kb * 8];
            #pragma unroll
            for (int nf = 0; nf < 4; ++nf)
                acc1[mf][nf] = __builtin_amdgcn_mfma_f32_16x16x32_f16(afr, w1f[nf], acc1[mf][nf], 0, 0, 0);
        }

        // epilogue: bias+ReLU -> slab (parity-split + bank-swizzle)
        #pragma unroll
        for (int mf = 0; mf < 3; ++mf) {
            #pragma unroll
            for (int nf = 0; nf < 4; ++nf) {
                const int c1 = nf * 16 + lrow;
                #pragma unroll
                for (int r = 0; r < 4; ++r) {
                    const int pp = ch * 192 + (wave * 3 + mf) * 16 + kb * 4 + r;
                    const int rowl = pp >> 6, xcol = pp & 63;
                    float v = fmaxf(acc1[mf][nf][r] + b1v[nf], 0.0f);
                    if (mc == 7 && rowl == 8) v = 0.0f;       // y=64 pad row
                    const int psx = ((xcol & 1) << 5) | (xcol >> 1);
                    const int c1s = c1 ^ ((psx & 7) << 3);
                    slab[(rowl * 64 + psx) * 64 + c1s] = (_Float16)v;
                }
            }
        }
        __syncthreads();                     // A1 reused next chunk; last one fences slab
    }

    // ---- phase 2: conv2, 9 taps, barrier-free. B prefetched to regs (static dbuf).
    f32x4 acc2[4][4];
    #pragma unroll
    for (int mf = 0; mf < 4; ++mf)
        #pragma unroll
        for (int nf = 0; nf < 4; ++nf)
            #pragma unroll
            for (int r = 0; r < 4; ++r) acc2[mf][nf][r] = 0.0f;

#define BLOAD(dst, tapi)                                                          \
    _Pragma("unroll")                                                             \
    for (int c1h = 0; c1h < 2; ++c1h)                                             \
        _Pragma("unroll")                                                         \
        for (int nf = 0; nf < 4; ++nf)                                            \
            dst[c1h * 4 + nf] = *(const f16x8*)(Bt2 + (size_t)(tapi) * 8192 +     \
                (wn * 64 + nf * 16 + lrow) * 64 + c1h * 32 + kb * 8);

#define TAPSTEP(tapi, BC)                                                         \
    {                                                                             \
        constexpr int kh_ = (tapi) / 3, kw_ = (tapi) % 3, par_ = kw_ & 1;         \
        _Pragma("unroll")                                                         \
        for (int c1h = 0; c1h < 2; ++c1h) {                                       \
            const int jt = c1h * 4 + kb;                                          \
            f16x8 afr[4];                                                         \
            _Pragma("unroll")                                                     \
            for (int mf = 0; mf < 4; ++mf) {                                      \
                const int ml  = wq * 64 + mf * 16 + lrow;                         \
                const int oyl = ml >> 5, ox = ml & 31;                            \
                const int p   = (2 * oyl + kh_) * 64 + par_ * 32 + (ox + (kw_ >> 1)); \
                f16x8 v = *(const f16x8*)&slab[p * 64 + (jt ^ (p & 7)) * 8];      \
                if (kw_ == 2 && ox == 31) v = (f16x8){};                          \
                afr[mf] = v;                                                      \
            }                                                                     \
            _Pragma("unroll")                                                     \
            for (int nf = 0; nf < 4; ++nf)                                        \
                _Pragma("unroll")                                                 \
                for (int mf = 0; mf < 4; ++mf)                                    \
                    acc2[mf][nf] = __builtin_amdgcn_mfma_f32_16x16x32_f16(        \
                        afr[mf], BC[c1h * 4 + nf], acc2[mf][nf], 0, 0, 0);        \
        }                                                                         \
    }

    f16x8 bA[8], bB[8];
    BLOAD(bA, 0)
    BLOAD(bB, 1)  TAPSTEP(0, bA)
    BLOAD(bA, 2)  TAPSTEP(1, bB)
    BLOAD(bB, 3)  TAPSTEP(2, bA)
    BLOAD(bA, 4)  TAPSTEP(3, bB)
    BLOAD(bB, 5)  TAPSTEP(4, bA)
    BLOAD(bA, 6)  TAPSTEP(5, bB)
    BLOAD(bB, 7)  TAPSTEP(6, bA)
    BLOAD(bA, 8)  TAPSTEP(7, bB)
                  TAPSTEP(8, bA)

    // ---- out: [bk][128][32][32]
    float* ob = out + (size_t)bk * 131072;
    #pragma unroll
    for (int mf = 0; mf < 4; ++mf) {
        const int m0 = mc * 128 + wq * 64 + mf * 16 + kb * 4;
        #pragma unroll
        for (int nf = 0; nf < 4; ++nf) {
            const int c2 = wn * 64 + nf * 16 + lrow;
            f32x4 v;
            #pragma unroll
            for (int r = 0; r < 4; ++r) v[r] = fmaxf(acc2[mf][nf][r] + b2v[nf], 0.0f);
            *(f32x4*)(ob + (size_t)c2 * 1024 + m0) = v;
        }
    }
}

extern "C" void kernel_launch(void* const* d_in, const int* in_sizes, int n_in,
                              void* d_out, int out_size, void* d_ws, size_t ws_size,
                              hipStream_t stream) {
    const float* x  = (const float*)d_in[0];
    const float* l  = (const float*)d_in[1];
    const float* w1 = (const float*)d_in[2];
    const float* b1 = (const float*)d_in[3];
    const float* w2 = (const float*)d_in[4];
    const float* b2 = (const float*)d_in[5];
    float* out = (float*)d_out;

    _Float16* Bt1 = (_Float16*)d_ws;         // 2048 f16
    _Float16* Bt2 = Bt1 + 64 * 32;           // 73728 f16

    transform_kernel<<<296, 256, 0, stream>>>(w1, w2, Bt1, Bt2);
    fused_kernel<<<dim3(8, 192), 256, 0, stream>>>(x, l, Bt1, b1, Bt2, b2, out);
}